// Round 2
// baseline (703.553 us; speedup 1.0000x reference)
//
#include <hip/hip_runtime.h>

// ---------------- problem constants (from reference) ----------------
#define N_NODES 5120
#define C_DIM   128
#define D_PE    16
#define M_MAX   256
#define B_G     32
#define H_HEADS 8
#define DH      16
#define EPS_PE  1e-8f
#define QT      4          // query rows per bias+attn block

// ---------------- ws layout (units: floats / int32) ----------------
#define WS_COUNTS   0         // 32 int
#define WS_OFFSETS  32        // 32 int
#define WS_INTRA    64        // 5120 int
#define WS_MASK     5184      // 8192 int
#define WS_HD       13376     // B*M*C   = 1048576
#define WS_AR       1061952   // B*M*16  = 131072
#define WS_AI       1193024   // 131072
#define WS_PN       1324096   // 131072
#define WS_Q        1455168   // 1048576
#define WS_K        2503744   // 1048576
#define WS_V        3552320   // 1048576
#define WS_OATT     4600896   // 1048576
#define WS_OPROJ    5649472   // 1048576
#define WS_HLN      6698048   // N*C = 655360
#define WS_FFNH     7353408   // N*2C = 1310720
#define WS_FFNO     8664128   // 655360
#define WS_TOTAL_FLOATS 9319488
#define WS_ZERO_FLOATS  1324096   // counts..ai must be zero each call

// ---------------- setup: counts -> offsets -> intra ----------------
__global__ __launch_bounds__(256) void setup_kernel(
    const int* __restrict__ batch, int* __restrict__ offsets, int* __restrict__ intra)
{
    __shared__ int cnt[B_G];
    __shared__ int off[B_G];
    const int t = threadIdx.x;
    if (t < B_G) cnt[t] = 0;
    __syncthreads();
    for (int n = t; n < N_NODES; n += 256) atomicAdd(&cnt[batch[n]], 1);
    __syncthreads();
    if (t == 0) {
        int s = 0;
        for (int b = 0; b < B_G; ++b) { off[b] = s; s += cnt[b]; }
    }
    __syncthreads();
    if (t < B_G) offsets[t] = off[t];
    for (int n = t; n < N_NODES; n += 256) intra[n] = n - off[batch[n]];
}

// ---------------- scatter ragged -> dense ----------------
__global__ __launch_bounds__(128) void scatter_kernel(
    const float* __restrict__ x, const float* __restrict__ pre, const float* __restrict__ pim,
    const int* __restrict__ batch, const int* __restrict__ intra,
    float* __restrict__ hd, float* __restrict__ ar, float* __restrict__ ai,
    int* __restrict__ mask)
{
    const int n = blockIdx.x;
    const int c = threadIdx.x;
    const int b = batch[n];
    const int m = intra[n];
    hd[((size_t)b * M_MAX + m) * C_DIM + c] = x[(size_t)n * C_DIM + c];
    if (c < D_PE) {
        ar[((size_t)b * M_MAX + m) * D_PE + c] = pre[(size_t)n * D_PE + c];
        ai[((size_t)b * M_MAX + m) * D_PE + c] = pim[(size_t)n * D_PE + c];
    }
    if (c == 0) mask[b * M_MAX + m] = 1;
}

// ---------------- pn = sqrt(ar^2 + ai^2 + EPS) ----------------
__global__ __launch_bounds__(256) void pn_kernel(
    const float* __restrict__ ar, const float* __restrict__ ai, float* __restrict__ pn)
{
    const int total = B_G * M_MAX * D_PE;
    for (int i = blockIdx.x * 256 + threadIdx.x; i < total; i += gridDim.x * 256) {
        float a = ar[i], b = ai[i];
        pn[i] = sqrtf(a * a + b * b + EPS_PE);
    }
}

// ---------------- generic small GEMM: out = act(A@W + bias) [+ res] ----------------
// A: [R, K] row-major, W: [K, COUT] row-major. R must be a multiple of 32.
template<int K, int COUT, bool RELU, bool RES>
__global__ __launch_bounds__(256) void gemm_kernel(
    const float* __restrict__ A, const float* __restrict__ W,
    const float* __restrict__ bias, const float* __restrict__ res,
    float* __restrict__ out)
{
    __shared__ float sA[32 * K];
    const int r0 = blockIdx.x * 32;
    const int t = threadIdx.x;
    #pragma unroll
    for (int i = 0; i < (32 * K) / 256; ++i)
        sA[t + i * 256] = A[(size_t)r0 * K + t + i * 256];
    __syncthreads();

    constexpr int ROWS = (COUT == 128) ? 16 : 32;
    const int c  = (COUT == 128) ? (t & 127) : t;
    const int rg = (COUT == 128) ? (t >> 7) : 0;

    float acc[ROWS];
    #pragma unroll
    for (int r = 0; r < ROWS; ++r) acc[r] = 0.f;

    #pragma unroll 4
    for (int kk = 0; kk < K; ++kk) {
        float w = W[(size_t)kk * COUT + c];
        #pragma unroll
        for (int r = 0; r < ROWS; ++r)
            acc[r] = fmaf(sA[(rg * ROWS + r) * K + kk], w, acc[r]);
    }

    const float bv = bias[c];
    #pragma unroll
    for (int r = 0; r < ROWS; ++r) {
        const int row = r0 + rg * ROWS + r;
        float v = acc[r] + bv;
        if (RELU) v = fmaxf(v, 0.f);
        if (RES)  v += res[(size_t)row * COUT + c];
        out[(size_t)row * COUT + c] = v;
    }
}

// ---------------- fused pairwise-bias MLP + attention ----------------
// grid: (M/QT, B). block: 256 threads; thread t == key index j.
// bias[b,h,q=i,k=j] = hb[b, m1=j, m2=i, h] with features
//   [ pn_j (16) | pn_i (16) | real_ji (16) | imag_ji (16) ]
//   real = (ar_j.ar_i + ai_j.ai_i)/(pn_j*pn_i+EPS), imag = (ai_j*ar_i - ar_j*ai_i)/(.)
__global__ __launch_bounds__(256) void bias_attn_kernel(
    const float* __restrict__ pn, const float* __restrict__ ar, const float* __restrict__ ai,
    const float* __restrict__ qm, const float* __restrict__ km, const float* __restrict__ vm,
    const int* __restrict__ mask,
    const float* __restrict__ w1, const float* __restrict__ b1,
    const float* __restrict__ w2, const float* __restrict__ b2,
    float* __restrict__ o_att)
{
    const int b  = blockIdx.y;
    const int i0 = blockIdx.x * QT;
    const int t  = threadIdx.x;
    const int j  = t;

    __shared__ float s_pni[QT][D_PE], s_ari[QT][D_PE], s_aii[QT][D_PE];
    __shared__ float s_q[QT][C_DIM];
    __shared__ float s_sc[QT][H_HEADS][M_MAX];   // scores -> probs (32 KB)

    // stage query-row data
    for (int idx = t; idx < QT * D_PE; idx += 256) {
        const int qi = idx / D_PE, dd = idx % D_PE;
        const size_t g = ((size_t)b * M_MAX + i0 + qi) * D_PE + dd;
        s_pni[qi][dd] = pn[g]; s_ari[qi][dd] = ar[g]; s_aii[qi][dd] = ai[g];
    }
    for (int idx = t; idx < QT * C_DIM; idx += 256) {
        const int qi = idx / C_DIM, c = idx % C_DIM;
        s_q[qi][c] = qm[((size_t)b * M_MAX + i0 + qi) * C_DIM + c];
    }
    __syncthreads();

    // per-thread key-row data (vectorized)
    float pnj[D_PE], arj[D_PE], aij[D_PE];
    {
        const size_t base = ((size_t)b * M_MAX + j) * D_PE;
        #pragma unroll
        for (int q4 = 0; q4 < 4; ++q4) {
            float4 v0 = ((const float4*)(pn + base))[q4];
            float4 v1 = ((const float4*)(ar + base))[q4];
            float4 v2 = ((const float4*)(ai + base))[q4];
            pnj[q4*4+0]=v0.x; pnj[q4*4+1]=v0.y; pnj[q4*4+2]=v0.z; pnj[q4*4+3]=v0.w;
            arj[q4*4+0]=v1.x; arj[q4*4+1]=v1.y; arj[q4*4+2]=v1.z; arj[q4*4+3]=v1.w;
            aij[q4*4+0]=v2.x; aij[q4*4+1]=v2.y; aij[q4*4+2]=v2.z; aij[q4*4+3]=v2.w;
        }
    }
    const int mj = mask[b * M_MAX + j];

    // bias MLP for QT query rows (weights via uniform/scalar loads)
    for (int qi = 0; qi < QT; ++qi) {
        float feat[64];
        #pragma unroll
        for (int dd = 0; dd < D_PE; ++dd) {
            const float pi  = s_pni[qi][dd];
            const float arI = s_ari[qi][dd];
            const float aiI = s_aii[qi][dd];
            const float den = pnj[dd] * pi + EPS_PE;
            const float inv = 1.0f / den;
            feat[dd]      = pnj[dd];
            feat[16 + dd] = pi;
            feat[32 + dd] = (arj[dd] * arI + aij[dd] * aiI) * inv;
            feat[48 + dd] = (aij[dd] * arI - arj[dd] * aiI) * inv;
        }
        float hid[32];
        #pragma unroll
        for (int hh = 0; hh < 32; ++hh) hid[hh] = b1[hh];
        #pragma unroll
        for (int f = 0; f < 64; ++f) {
            const float fv = feat[f];
            #pragma unroll
            for (int hh = 0; hh < 32; ++hh)
                hid[hh] = fmaf(fv, w1[f * 32 + hh], hid[hh]);
        }
        #pragma unroll
        for (int hh = 0; hh < 32; ++hh) hid[hh] = fmaxf(hid[hh], 0.f);
        #pragma unroll
        for (int h = 0; h < H_HEADS; ++h) {
            float o = b2[h];
            #pragma unroll
            for (int hh = 0; hh < 32; ++hh)
                o = fmaf(hid[hh], w2[hh * H_HEADS + h], o);
            s_sc[qi][h][j] = o;          // bias; qk added below
        }
    }

    // QK^T / sqrt(dh) + bias, key-padding mask
    {
        const float* krow = km + ((size_t)b * M_MAX + j) * C_DIM;
        #pragma unroll
        for (int h = 0; h < H_HEADS; ++h) {
            float kv[DH];
            #pragma unroll
            for (int q4 = 0; q4 < 4; ++q4) {
                float4 v = ((const float4*)(krow + h * DH))[q4];
                kv[q4*4+0]=v.x; kv[q4*4+1]=v.y; kv[q4*4+2]=v.z; kv[q4*4+3]=v.w;
            }
            for (int qi = 0; qi < QT; ++qi) {
                float dot = 0.f;
                #pragma unroll
                for (int dd = 0; dd < DH; ++dd)
                    dot = fmaf(s_q[qi][h * DH + dd], kv[dd], dot);
                const float sc = s_sc[qi][h][j] + dot * 0.25f;
                s_sc[qi][h][j] = mj ? sc : -1e9f;
            }
        }
    }
    __syncthreads();

    // softmax over keys: 32 rows of 256; wave w handles rows w, w+4, ...
    {
        const int wave = t >> 6, lane = t & 63;
        for (int r = wave; r < QT * H_HEADS; r += 4) {
            float* row = ((float*)s_sc) + r * M_MAX;
            float x0 = row[lane], x1 = row[lane + 64], x2 = row[lane + 128], x3 = row[lane + 192];
            float mx = fmaxf(fmaxf(x0, x1), fmaxf(x2, x3));
            #pragma unroll
            for (int off = 32; off > 0; off >>= 1) mx = fmaxf(mx, __shfl_xor(mx, off, 64));
            float e0 = expf(x0 - mx), e1 = expf(x1 - mx), e2 = expf(x2 - mx), e3 = expf(x3 - mx);
            float s = e0 + e1 + e2 + e3;
            #pragma unroll
            for (int off = 32; off > 0; off >>= 1) s += __shfl_xor(s, off, 64);
            const float inv = 1.f / s;
            row[lane] = e0 * inv; row[lane + 64] = e1 * inv;
            row[lane + 128] = e2 * inv; row[lane + 192] = e3 * inv;
        }
    }
    __syncthreads();

    // PV: thread (c = t&127, g = t>>7) computes 2 query rows for its column
    {
        const int c = t & 127;
        const int g = t >> 7;
        const int h = c >> 4;
        const int qA = g * 2, qB = g * 2 + 1;
        const float* vb = vm + (size_t)b * M_MAX * C_DIM;
        float acc0 = 0.f, acc1 = 0.f;
        for (int jj = 0; jj < M_MAX; ++jj) {
            const float vv = vb[(size_t)jj * C_DIM + c];
            acc0 = fmaf(s_sc[qA][h][jj], vv, acc0);
            acc1 = fmaf(s_sc[qB][h][jj], vv, acc1);
        }
        o_att[((size_t)b * M_MAX + i0 + qA) * C_DIM + c] = acc0;
        o_att[((size_t)b * M_MAX + i0 + qB) * C_DIM + c] = acc1;
    }
}

// ---------------- gather + residual + LayerNorm ----------------
__global__ __launch_bounds__(128) void gather_res_ln_kernel(
    const float* __restrict__ op, const float* __restrict__ x,
    const int* __restrict__ batch, const int* __restrict__ intra,
    const float* __restrict__ g, const float* __restrict__ be, float* __restrict__ out)
{
    const int n = blockIdx.x, c = threadIdx.x;
    const int b = batch[n], m = intra[n];
    const float v = op[((size_t)b * M_MAX + m) * C_DIM + c] + x[(size_t)n * C_DIM + c];
    float s = v, sq = v * v;
    #pragma unroll
    for (int off = 32; off > 0; off >>= 1) {
        s  += __shfl_xor(s, off, 64);
        sq += __shfl_xor(sq, off, 64);
    }
    __shared__ float red[4];
    if ((threadIdx.x & 63) == 0) {
        red[(threadIdx.x >> 6) * 2]     = s;
        red[(threadIdx.x >> 6) * 2 + 1] = sq;
    }
    __syncthreads();
    s = red[0] + red[2]; sq = red[1] + red[3];
    const float mu  = s * (1.f / C_DIM);
    const float var = sq * (1.f / C_DIM) - mu * mu;
    const float sc  = rsqrtf(var + 1e-5f);
    out[(size_t)n * C_DIM + c] = (v - mu) * sc * g[c] + be[c];
}

// ---------------- plain LayerNorm (final) ----------------
__global__ __launch_bounds__(128) void ln_kernel(
    const float* __restrict__ in, const float* __restrict__ g,
    const float* __restrict__ be, float* __restrict__ out)
{
    const int n = blockIdx.x, c = threadIdx.x;
    const float v = in[(size_t)n * C_DIM + c];
    float s = v, sq = v * v;
    #pragma unroll
    for (int off = 32; off > 0; off >>= 1) {
        s  += __shfl_xor(s, off, 64);
        sq += __shfl_xor(sq, off, 64);
    }
    __shared__ float red[4];
    if ((threadIdx.x & 63) == 0) {
        red[(threadIdx.x >> 6) * 2]     = s;
        red[(threadIdx.x >> 6) * 2 + 1] = sq;
    }
    __syncthreads();
    s = red[0] + red[2]; sq = red[1] + red[3];
    const float mu  = s * (1.f / C_DIM);
    const float var = sq * (1.f / C_DIM) - mu * mu;
    const float sc  = rsqrtf(var + 1e-5f);
    out[(size_t)n * C_DIM + c] = (v - mu) * sc * g[c] + be[c];
}

// ---------------- launch ----------------
extern "C" void kernel_launch(void* const* d_in, const int* in_sizes, int n_in,
                              void* d_out, int out_size, void* d_ws, size_t ws_size,
                              hipStream_t stream)
{
    const float* x      = (const float*)d_in[0];
    const float* pe_re  = (const float*)d_in[1];
    const float* pe_im  = (const float*)d_in[2];
    const float* wq     = (const float*)d_in[3];
    const float* bq     = (const float*)d_in[4];
    const float* wk     = (const float*)d_in[5];
    const float* bk     = (const float*)d_in[6];
    const float* wv     = (const float*)d_in[7];
    const float* bv     = (const float*)d_in[8];
    const float* wo     = (const float*)d_in[9];
    const float* bo     = (const float*)d_in[10];
    const float* pe_w1  = (const float*)d_in[11];
    const float* pe_b1  = (const float*)d_in[12];
    const float* pe_w2  = (const float*)d_in[13];
    const float* pe_b2  = (const float*)d_in[14];
    const float* mlp_w1 = (const float*)d_in[15];
    const float* mlp_b1 = (const float*)d_in[16];
    const float* mlp_w2 = (const float*)d_in[17];
    const float* mlp_b2 = (const float*)d_in[18];
    const float* ln2_g  = (const float*)d_in[19];
    const float* ln2_b  = (const float*)d_in[20];
    const float* ln3_g  = (const float*)d_in[21];
    const float* ln3_b  = (const float*)d_in[22];
    const int*   batch  = (const int*)d_in[23];
    // d_in[24] edge_index: unused by reference; d_in[25] nmax: hardcoded 256

    float* ws = (float*)d_ws;
    int*   offsets = (int*)(ws + WS_OFFSETS);
    int*   intra   = (int*)(ws + WS_INTRA);
    int*   mask    = (int*)(ws + WS_MASK);
    float* hd   = ws + WS_HD;
    float* ar   = ws + WS_AR;
    float* ai   = ws + WS_AI;
    float* pn   = ws + WS_PN;
    float* qm   = ws + WS_Q;
    float* km   = ws + WS_K;
    float* vm   = ws + WS_V;
    float* oatt = ws + WS_OATT;
    float* oprj = ws + WS_OPROJ;
    float* hln  = ws + WS_HLN;
    float* ffnh = ws + WS_FFNH;
    float* ffno = ws + WS_FFNO;
    float* outp = (float*)d_out;

    // zero counts/offsets/intra/mask/hd/ar/ai (re-poisoned to 0xAA each call)
    hipMemsetAsync(d_ws, 0, (size_t)WS_ZERO_FLOATS * sizeof(float), stream);

    setup_kernel<<<1, 256, 0, stream>>>(batch, offsets, intra);
    scatter_kernel<<<N_NODES, 128, 0, stream>>>(x, pe_re, pe_im, batch, intra, hd, ar, ai, mask);
    pn_kernel<<<512, 256, 0, stream>>>(ar, ai, pn);

    gemm_kernel<128, 128, false, false><<<256, 256, 0, stream>>>(hd, wq, bq, nullptr, qm);
    gemm_kernel<128, 128, false, false><<<256, 256, 0, stream>>>(hd, wk, bk, nullptr, km);
    gemm_kernel<128, 128, false, false><<<256, 256, 0, stream>>>(hd, wv, bv, nullptr, vm);

    bias_attn_kernel<<<dim3(M_MAX / QT, B_G), 256, 0, stream>>>(
        pn, ar, ai, qm, km, vm, mask, pe_w1, pe_b1, pe_w2, pe_b2, oatt);

    gemm_kernel<128, 128, false, false><<<256, 256, 0, stream>>>(oatt, wo, bo, nullptr, oprj);

    gather_res_ln_kernel<<<N_NODES, 128, 0, stream>>>(oprj, x, batch, intra, ln2_g, ln2_b, hln);

    gemm_kernel<128, 256, true,  false><<<160, 256, 0, stream>>>(hln, mlp_w1, mlp_b1, nullptr, ffnh);
    gemm_kernel<256, 128, false, true ><<<160, 256, 0, stream>>>(ffnh, mlp_w2, mlp_b2, hln, ffno);

    ln_kernel<<<N_NODES, 128, 0, stream>>>(ffno, ln3_g, ln3_b, outp);
}

// Round 3
// 335.493 us; speedup vs baseline: 2.0971x; 2.0971x over previous
//
#include <hip/hip_runtime.h>

// ---------------- problem constants ----------------
#define N_NODES 5120
#define C_DIM   128
#define D_PE    16
#define M_MAX   256
#define B_G     32
#define H_HEADS 8
#define DH      16
#define EPS_PE  1e-8f
#define QT      4
#define SCP     264   // padded score stride (kills 4-way PV bank conflict)

// ---------------- ws layout (float units) ----------------
#define WS_COUNTS   0
#define WS_OFFSETS  32
#define WS_INTRA    64
#define WS_MASK     5184
#define WS_HD       13376      // B*M*C = 1048576
#define WS_AR       1061952    // 131072
#define WS_AI       1193024    // 131072
#define WS_PN       1324096    // 131072
#define WS_CN       1455168    // B*M*32 = 262144 (f32 unit complex [cr|ci])
#define WS_KFHI     1717312    // B*M*64 bf16 = 262144 f
#define WS_KFLO     1979456    // B*M*32 bf16 = 131072 f
#define WS_Q        2110528    // 1048576
#define WS_K        3159104
#define WS_V        4207680
#define WS_OATT     5256256
#define WS_OPROJ    6304832
#define WS_HLN      7353408    // 655360
#define WS_FFNH     8008768    // 1310720
#define WS_FFNO     9319488    // 655360
#define WS_BIAS     9974848    // B*M*M*8 bf16 = 8388608 f
#define WS_ZERO_FLOATS 1324096 // counts..ai zeroed each call

typedef __attribute__((ext_vector_type(8))) short bf8_t;
typedef __attribute__((ext_vector_type(4))) float f4_t;

__device__ inline short f2bf(float f) {
    union { float f; unsigned u; } v; v.f = f;
    unsigned r = (v.u + 0x7FFF + ((v.u >> 16) & 1)) >> 16;
    return (short)r;
}
__device__ inline float bf2f(short h) {
    union { unsigned u; float f; } v; v.u = ((unsigned)(unsigned short)h) << 16;
    return v.f;
}
__device__ inline unsigned pack2(short a, short b) {
    return (unsigned)(unsigned short)a | ((unsigned)(unsigned short)b << 16);
}
__device__ inline bf8_t bf8_from2(uint2 a, uint2 b) {
    bf8_t o;
    o[0]=(short)a.x; o[1]=(short)(a.x>>16); o[2]=(short)a.y; o[3]=(short)(a.y>>16);
    o[4]=(short)b.x; o[5]=(short)(b.x>>16); o[6]=(short)b.y; o[7]=(short)(b.y>>16);
    return o;
}

// ---------------- setup: counts -> offsets -> intra ----------------
__global__ __launch_bounds__(256) void setup_kernel(
    const int* __restrict__ batch, int* __restrict__ offsets, int* __restrict__ intra)
{
    __shared__ int cnt[B_G];
    __shared__ int off[B_G];
    const int t = threadIdx.x;
    if (t < B_G) cnt[t] = 0;
    __syncthreads();
    for (int n = t; n < N_NODES; n += 256) atomicAdd(&cnt[batch[n]], 1);
    __syncthreads();
    if (t == 0) { int s = 0; for (int b = 0; b < B_G; ++b) { off[b] = s; s += cnt[b]; } }
    __syncthreads();
    if (t < B_G) offsets[t] = off[t];
    for (int n = t; n < N_NODES; n += 256) intra[n] = n - off[batch[n]];
}

// ---------------- scatter ragged -> dense ----------------
__global__ __launch_bounds__(128) void scatter_kernel(
    const float* __restrict__ x, const float* __restrict__ pre, const float* __restrict__ pim,
    const int* __restrict__ batch, const int* __restrict__ intra,
    float* __restrict__ hd, float* __restrict__ ar, float* __restrict__ ai,
    int* __restrict__ mask)
{
    const int n = blockIdx.x, c = threadIdx.x;
    const int b = batch[n], m = intra[n];
    hd[((size_t)b * M_MAX + m) * C_DIM + c] = x[(size_t)n * C_DIM + c];
    if (c < D_PE) {
        ar[((size_t)b * M_MAX + m) * D_PE + c] = pre[(size_t)n * D_PE + c];
        ai[((size_t)b * M_MAX + m) * D_PE + c] = pim[(size_t)n * D_PE + c];
    }
    if (c == 0) mask[b * M_MAX + m] = 1;
}

// ---------------- prep: pn, unit complex, key features (bf16 hi/lo) ----------------
__global__ __launch_bounds__(256) void prep_kernel(
    const float* __restrict__ ar, const float* __restrict__ ai,
    float* __restrict__ pn, float* __restrict__ cn,
    unsigned short* __restrict__ kf_hi, unsigned short* __restrict__ kf_lo)
{
    const int idx = blockIdx.x * 256 + threadIdx.x;     // B*M*16 = 131072
    const int cell = idx >> 4, dd = idx & 15;
    const float a = ar[idx], b = ai[idx];
    const float p = sqrtf(a * a + b * b + EPS_PE);
    const float inv = 1.f / p;
    const float cr = a * inv, ci = b * inv;
    pn[idx] = p;
    cn[(size_t)cell * 32 + dd]      = cr;
    cn[(size_t)cell * 32 + 16 + dd] = ci;
    const size_t hb = (size_t)cell * 64, lb = (size_t)cell * 32;
    short crh = f2bf(cr), cih = f2bf(ci);
    kf_hi[hb + dd]      = (unsigned short)crh;
    kf_hi[hb + 16 + dd] = (unsigned short)cih;
    kf_hi[hb + 32 + dd] = (unsigned short)f2bf(p);
    kf_hi[hb + 48 + dd] = (dd == 0) ? (unsigned short)f2bf(1.f) : 0;
    kf_lo[lb + dd]      = (unsigned short)f2bf(cr - bf2f(crh));
    kf_lo[lb + 16 + dd] = (unsigned short)f2bf(ci - bf2f(cih));
}

// ---------------- generic small GEMM (unchanged, passed) ----------------
template<int K, int COUT, bool RELU, bool RES>
__global__ __launch_bounds__(256) void gemm_kernel(
    const float* __restrict__ A, const float* __restrict__ W,
    const float* __restrict__ bias, const float* __restrict__ res,
    float* __restrict__ out)
{
    __shared__ float sA[32 * K];
    const int r0 = blockIdx.x * 32;
    const int t = threadIdx.x;
    #pragma unroll
    for (int i = 0; i < (32 * K) / 256; ++i)
        sA[t + i * 256] = A[(size_t)r0 * K + t + i * 256];
    __syncthreads();

    constexpr int ROWS = (COUT == 128) ? 16 : 32;
    const int c  = (COUT == 128) ? (t & 127) : t;
    const int rg = (COUT == 128) ? (t >> 7) : 0;

    float acc[ROWS];
    #pragma unroll
    for (int r = 0; r < ROWS; ++r) acc[r] = 0.f;

    #pragma unroll 4
    for (int kk = 0; kk < K; ++kk) {
        float w = W[(size_t)kk * COUT + c];
        #pragma unroll
        for (int r = 0; r < ROWS; ++r)
            acc[r] = fmaf(sA[(rg * ROWS + r) * K + kk], w, acc[r]);
    }

    const float bv = bias[c];
    #pragma unroll
    for (int r = 0; r < ROWS; ++r) {
        const int row = r0 + rg * ROWS + r;
        float v = acc[r] + bv;
        if (RELU) v = fmaxf(v, 0.f);
        if (RES)  v += res[(size_t)row * COUT + c];
        out[(size_t)row * COUT + c] = v;
    }
}

// ---------------- MFMA pairwise-bias kernel ----------------
// bias[b][i][j][h] = b2[h] + relu(hid)[hh]@w2 ; hid separable:
//   hid[hh] = sum_k W_i[k][hh] * keyfeat_j[k],  k: [cr16|ci16|pn16|1,0..]
// W_i[k<16]   = W1[32+k]*cr_i[k]  - W1[48+k]*ci_i[k]
// W_i[16..31] = W1[32+d]*ci_i[d]  + W1[48+d]*cr_i[d]   (d=k-16)
// W_i[32..47] = W1[k-32]   (pn_j rows, const)
// W_i[48]     = v_i + b1,  v_i[hh] = sum_d W1[16+d][hh]*pn_i[d]
__global__ __launch_bounds__(512) void bias_kernel(
    const float* __restrict__ cn, const float* __restrict__ pn,
    const unsigned short* __restrict__ kf_hi, const unsigned short* __restrict__ kf_lo,
    const float* __restrict__ w1, const float* __restrict__ b1,
    const float* __restrict__ w2, const float* __restrict__ b2,
    unsigned short* __restrict__ bias_out)
{
    __shared__ float sW1T[32][65];     // [hh][f] padded
    __shared__ float s_cn[16][32];
    __shared__ float s_pn[16][16];
    __shared__ uint2 s_scr[8][16][10]; // per-wave scratch: [j][hh*2B], 80B rows

    const int b  = blockIdx.y;
    const int i0 = blockIdx.x * 16;
    const int t  = threadIdx.x;

    for (int idx = t; idx < 2048; idx += 512) {
        int f = idx >> 5, hh = idx & 31;
        sW1T[hh][f] = w1[f * 32 + hh];
    }
    { int il = t >> 5, c = t & 31;
      s_cn[il][c] = cn[((size_t)(b * 256 + i0 + il)) * 32 + c]; }
    if (t < 256) { int il = t >> 4, dd = t & 15;
      s_pn[il][dd] = pn[((size_t)(b * 256 + i0 + il)) * 16 + dd]; }
    __syncthreads();

    const int w    = t >> 6;
    const int lane = t & 63;
    const int lj   = lane & 15;
    const int g    = lane >> 4;

    // constant A2 frag: A2[row=h'][k=hh] = w2[hh][h'] (h'>=8 -> 0), plain bf16
    bf8_t a2f;
    #pragma unroll
    for (int e = 0; e < 8; ++e) {
        float v = (lj < 8) ? w2[(g * 8 + e) * 8 + lj] : 0.f;
        a2f[e] = f2bf(v);
    }
    float b2v0 = 0.f, b2v1 = 0.f, b2v2 = 0.f, b2v3 = 0.f;
    if (g < 2) { b2v0 = b2[g*4+0]; b2v1 = b2[g*4+1]; b2v2 = b2[g*4+2]; b2v3 = b2[g*4+3]; }

    for (int ii = 0; ii < 2; ++ii) {
        const int il = w * 2 + ii;
        const int i  = i0 + il;

        // v_i + b1 (both hh tiles)
        float vrow0 = b1[lj], vrow1 = b1[16 + lj];
        #pragma unroll
        for (int dd = 0; dd < 16; ++dd) {
            float p = s_pn[il][dd];
            vrow0 = fmaf(sW1T[lj][16 + dd],      p, vrow0);
            vrow1 = fmaf(sW1T[16 + lj][16 + dd], p, vrow1);
        }

        // A frags: A[row=hh][k=(g*8+e)]
        bf8_t a0hi0, a0lo0, a1f0, a0hi1, a0lo1, a1f1;
        #pragma unroll
        for (int e = 0; e < 8; ++e) {
            const int dd = (g & 1) * 8 + e;
            const float cr = s_cn[il][dd], ci = s_cn[il][16 + dd];
            {   // tile0: hh = lj
                float wr = sW1T[lj][32 + dd], wi = sW1T[lj][48 + dd];
                float val = (g < 2) ? (wr * cr - wi * ci) : (wr * ci + wi * cr);
                short hi = f2bf(val);
                a0hi0[e] = hi; a0lo0[e] = f2bf(val - bf2f(hi));
                float v1 = (g < 2) ? sW1T[lj][g * 8 + e]
                                   : ((g == 2 && e == 0) ? vrow0 : 0.f);
                a1f0[e] = f2bf(v1);
            }
            {   // tile1: hh = 16+lj
                float wr = sW1T[16 + lj][32 + dd], wi = sW1T[16 + lj][48 + dd];
                float val = (g < 2) ? (wr * cr - wi * ci) : (wr * ci + wi * cr);
                short hi = f2bf(val);
                a0hi1[e] = hi; a0lo1[e] = f2bf(val - bf2f(hi));
                float v1 = (g < 2) ? sW1T[16 + lj][g * 8 + e]
                                   : ((g == 2 && e == 0) ? vrow1 : 0.f);
                a1f1[e] = f2bf(v1);
            }
        }

        for (int jt = 0; jt < 16; ++jt) {
            const size_t node = (size_t)b * 256 + jt * 16 + lj;
            const bf8_t* ph = (const bf8_t*)(kf_hi + node * 64);
            const bf8_t* pl = (const bf8_t*)(kf_lo + node * 32);
            bf8_t b0hi = ph[g];
            bf8_t b0lo = pl[g];
            bf8_t b1f  = ph[4 + g];

            f4_t acc0 = {0.f, 0.f, 0.f, 0.f}, acc1 = {0.f, 0.f, 0.f, 0.f};
            acc0 = __builtin_amdgcn_mfma_f32_16x16x32_bf16(a0hi0, b0hi, acc0, 0, 0, 0);
            acc0 = __builtin_amdgcn_mfma_f32_16x16x32_bf16(a0hi0, b0lo, acc0, 0, 0, 0);
            acc0 = __builtin_amdgcn_mfma_f32_16x16x32_bf16(a0lo0, b0hi, acc0, 0, 0, 0);
            acc0 = __builtin_amdgcn_mfma_f32_16x16x32_bf16(a1f0,  b1f,  acc0, 0, 0, 0);
            acc1 = __builtin_amdgcn_mfma_f32_16x16x32_bf16(a0hi1, b0hi, acc1, 0, 0, 0);
            acc1 = __builtin_amdgcn_mfma_f32_16x16x32_bf16(a0hi1, b0lo, acc1, 0, 0, 0);
            acc1 = __builtin_amdgcn_mfma_f32_16x16x32_bf16(a0lo1, b0hi, acc1, 0, 0, 0);
            acc1 = __builtin_amdgcn_mfma_f32_16x16x32_bf16(a1f1,  b1f,  acc1, 0, 0, 0);

            // relu + pack -> scratch [j=lj][hh]; lane holds hh = 4g+r (tiles 0/1), col j=lj
            uint2 w0, w1p;
            w0.x  = pack2(f2bf(fmaxf(acc0[0], 0.f)), f2bf(fmaxf(acc0[1], 0.f)));
            w0.y  = pack2(f2bf(fmaxf(acc0[2], 0.f)), f2bf(fmaxf(acc0[3], 0.f)));
            w1p.x = pack2(f2bf(fmaxf(acc1[0], 0.f)), f2bf(fmaxf(acc1[1], 0.f)));
            w1p.y = pack2(f2bf(fmaxf(acc1[2], 0.f)), f2bf(fmaxf(acc1[3], 0.f)));
            s_scr[w][lj][g]     = w0;    // hh 4g..4g+3
            s_scr[w][lj][4 + g] = w1p;   // hh 16+4g..+3
            __builtin_amdgcn_s_waitcnt(0); // lgkmcnt(0): wave-local scratch ready

            // B2 frag: [k=hh=8g..8g+7][col=j=lj]
            uint2 q0 = s_scr[w][lj][2 * g];
            uint2 q1 = s_scr[w][lj][2 * g + 1];
            bf8_t hb = bf8_from2(q0, q1);

            f4_t acc2 = {0.f, 0.f, 0.f, 0.f};
            acc2 = __builtin_amdgcn_mfma_f32_16x16x32_bf16(a2f, hb, acc2, 0, 0, 0);

            if (g < 2) {   // rows h' = 4g+r valid
                uint2 st;
                st.x = pack2(f2bf(acc2[0] + b2v0), f2bf(acc2[1] + b2v1));
                st.y = pack2(f2bf(acc2[2] + b2v2), f2bf(acc2[3] + b2v3));
                size_t idx = (((size_t)b * 256 + i) * 256 + jt * 16 + lj) * 8 + g * 4;
                *(uint2*)(bias_out + idx) = st;
            }
        }
    }
}

// ---------------- attention (bias from global, fp32 VALU) ----------------
__global__ __launch_bounds__(256) void attn_kernel(
    const float* __restrict__ qm, const float* __restrict__ km, const float* __restrict__ vm,
    const int* __restrict__ mask, const unsigned short* __restrict__ bias,
    float* __restrict__ o_att)
{
    const int b  = blockIdx.y;
    const int i0 = blockIdx.x * QT;
    const int t  = threadIdx.x;
    const int j  = t;

    __shared__ float s_q[QT][C_DIM];
    __shared__ float s_sc[QT][H_HEADS][SCP];

    for (int idx = t; idx < QT * C_DIM; idx += 256) {
        const int qi = idx >> 7, c = idx & 127;
        s_q[qi][c] = qm[((size_t)(b * 256 + i0 + qi)) * C_DIM + c];
    }
    __syncthreads();

    const int mj = mask[b * M_MAX + j];
    uint4 bu[QT];
    #pragma unroll
    for (int qi = 0; qi < QT; ++qi)
        bu[qi] = *(const uint4*)(bias + (((size_t)(b * 256 + i0 + qi)) * 256 + j) * 8);

    const float* krow = km + ((size_t)(b * 256 + j)) * C_DIM;
    #pragma unroll
    for (int h = 0; h < 8; ++h) {
        float kv[DH];
        #pragma unroll
        for (int q4 = 0; q4 < 4; ++q4) {
            float4 v = ((const float4*)(krow + h * DH))[q4];
            kv[q4*4+0]=v.x; kv[q4*4+1]=v.y; kv[q4*4+2]=v.z; kv[q4*4+3]=v.w;
        }
        #pragma unroll
        for (int qi = 0; qi < QT; ++qi) {
            float dot = 0.f;
            #pragma unroll
            for (int dd = 0; dd < DH; ++dd)
                dot = fmaf(s_q[qi][h * DH + dd], kv[dd], dot);
            const unsigned u = ((const unsigned*)&bu[qi])[h >> 1];
            const float bv = bf2f((short)((h & 1) ? (u >> 16) : (u & 0xffff)));
            s_sc[qi][h][j] = mj ? fmaf(dot, 0.25f, bv) : -1e9f;
        }
    }
    __syncthreads();

    {   // softmax: 32 rows of 256
        const int wave = t >> 6, lane = t & 63;
        for (int r = wave; r < QT * H_HEADS; r += 4) {
            float* row = ((float*)s_sc) + r * SCP;
            float x0 = row[lane], x1 = row[lane + 64], x2 = row[lane + 128], x3 = row[lane + 192];
            float mx = fmaxf(fmaxf(x0, x1), fmaxf(x2, x3));
            #pragma unroll
            for (int off = 32; off > 0; off >>= 1) mx = fmaxf(mx, __shfl_xor(mx, off, 64));
            float e0 = expf(x0 - mx), e1 = expf(x1 - mx), e2 = expf(x2 - mx), e3 = expf(x3 - mx);
            float s = e0 + e1 + e2 + e3;
            #pragma unroll
            for (int off = 32; off > 0; off >>= 1) s += __shfl_xor(s, off, 64);
            const float inv = 1.f / s;
            row[lane] = e0 * inv; row[lane + 64] = e1 * inv;
            row[lane + 128] = e2 * inv; row[lane + 192] = e3 * inv;
        }
    }
    __syncthreads();

    {   // PV: thread (c, gq) -> 2 query rows; float4 prob reads
        const int c = t & 127;
        const int gq = t >> 7;
        const int h = c >> 4;
        const int qA = gq * 2, qB = gq * 2 + 1;
        const float* vb = vm + (size_t)b * M_MAX * C_DIM + c;
        float a0 = 0.f, a1 = 0.f;
        for (int jj = 0; jj < M_MAX; jj += 4) {
            float4 pA = *(const float4*)&s_sc[qA][h][jj];
            float4 pB = *(const float4*)&s_sc[qB][h][jj];
            float v0 = vb[(size_t)(jj + 0) * C_DIM];
            float v1 = vb[(size_t)(jj + 1) * C_DIM];
            float v2 = vb[(size_t)(jj + 2) * C_DIM];
            float v3 = vb[(size_t)(jj + 3) * C_DIM];
            a0 = fmaf(pA.x, v0, a0); a0 = fmaf(pA.y, v1, a0);
            a0 = fmaf(pA.z, v2, a0); a0 = fmaf(pA.w, v3, a0);
            a1 = fmaf(pB.x, v0, a1); a1 = fmaf(pB.y, v1, a1);
            a1 = fmaf(pB.z, v2, a1); a1 = fmaf(pB.w, v3, a1);
        }
        o_att[((size_t)(b * 256 + i0 + qA)) * C_DIM + c] = a0;
        o_att[((size_t)(b * 256 + i0 + qB)) * C_DIM + c] = a1;
    }
}

// ---------------- gather + residual + LayerNorm ----------------
__global__ __launch_bounds__(128) void gather_res_ln_kernel(
    const float* __restrict__ op, const float* __restrict__ x,
    const int* __restrict__ batch, const int* __restrict__ intra,
    const float* __restrict__ g, const float* __restrict__ be, float* __restrict__ out)
{
    const int n = blockIdx.x, c = threadIdx.x;
    const int b = batch[n], m = intra[n];
    const float v = op[((size_t)b * M_MAX + m) * C_DIM + c] + x[(size_t)n * C_DIM + c];
    float s = v, sq = v * v;
    #pragma unroll
    for (int off = 32; off > 0; off >>= 1) {
        s  += __shfl_xor(s, off, 64);
        sq += __shfl_xor(sq, off, 64);
    }
    __shared__ float red[4];
    if ((threadIdx.x & 63) == 0) {
        red[(threadIdx.x >> 6) * 2]     = s;
        red[(threadIdx.x >> 6) * 2 + 1] = sq;
    }
    __syncthreads();
    s = red[0] + red[2]; sq = red[1] + red[3];
    const float mu  = s * (1.f / C_DIM);
    const float var = sq * (1.f / C_DIM) - mu * mu;
    const float sc  = rsqrtf(var + 1e-5f);
    out[(size_t)n * C_DIM + c] = (v - mu) * sc * g[c] + be[c];
}

__global__ __launch_bounds__(128) void ln_kernel(
    const float* __restrict__ in, const float* __restrict__ g,
    const float* __restrict__ be, float* __restrict__ out)
{
    const int n = blockIdx.x, c = threadIdx.x;
    const float v = in[(size_t)n * C_DIM + c];
    float s = v, sq = v * v;
    #pragma unroll
    for (int off = 32; off > 0; off >>= 1) {
        s  += __shfl_xor(s, off, 64);
        sq += __shfl_xor(sq, off, 64);
    }
    __shared__ float red[4];
    if ((threadIdx.x & 63) == 0) {
        red[(threadIdx.x >> 6) * 2]     = s;
        red[(threadIdx.x >> 6) * 2 + 1] = sq;
    }
    __syncthreads();
    s = red[0] + red[2]; sq = red[1] + red[3];
    const float mu  = s * (1.f / C_DIM);
    const float var = sq * (1.f / C_DIM) - mu * mu;
    const float sc  = rsqrtf(var + 1e-5f);
    out[(size_t)n * C_DIM + c] = (v - mu) * sc * g[c] + be[c];
}

// ---------------- launch ----------------
extern "C" void kernel_launch(void* const* d_in, const int* in_sizes, int n_in,
                              void* d_out, int out_size, void* d_ws, size_t ws_size,
                              hipStream_t stream)
{
    const float* x      = (const float*)d_in[0];
    const float* pe_re  = (const float*)d_in[1];
    const float* pe_im  = (const float*)d_in[2];
    const float* wq     = (const float*)d_in[3];
    const float* bq     = (const float*)d_in[4];
    const float* wk     = (const float*)d_in[5];
    const float* bk     = (const float*)d_in[6];
    const float* wv     = (const float*)d_in[7];
    const float* bv     = (const float*)d_in[8];
    const float* wo     = (const float*)d_in[9];
    const float* bo     = (const float*)d_in[10];
    const float* pe_w1  = (const float*)d_in[11];
    const float* pe_b1  = (const float*)d_in[12];
    const float* pe_w2  = (const float*)d_in[13];
    const float* pe_b2  = (const float*)d_in[14];
    const float* mlp_w1 = (const float*)d_in[15];
    const float* mlp_b1 = (const float*)d_in[16];
    const float* mlp_w2 = (const float*)d_in[17];
    const float* mlp_b2 = (const float*)d_in[18];
    const float* ln2_g  = (const float*)d_in[19];
    const float* ln2_b  = (const float*)d_in[20];
    const float* ln3_g  = (const float*)d_in[21];
    const float* ln3_b  = (const float*)d_in[22];
    const int*   batch  = (const int*)d_in[23];

    float* ws = (float*)d_ws;
    int*   offsets = (int*)(ws + WS_OFFSETS);
    int*   intra   = (int*)(ws + WS_INTRA);
    int*   mask    = (int*)(ws + WS_MASK);
    float* hd   = ws + WS_HD;
    float* ar   = ws + WS_AR;
    float* ai   = ws + WS_AI;
    float* pn   = ws + WS_PN;
    float* cn   = ws + WS_CN;
    unsigned short* kf_hi = (unsigned short*)(ws + WS_KFHI);
    unsigned short* kf_lo = (unsigned short*)(ws + WS_KFLO);
    float* qm   = ws + WS_Q;
    float* km   = ws + WS_K;
    float* vm   = ws + WS_V;
    float* oatt = ws + WS_OATT;
    float* oprj = ws + WS_OPROJ;
    float* hln  = ws + WS_HLN;
    float* ffnh = ws + WS_FFNH;
    float* ffno = ws + WS_FFNO;
    unsigned short* bias = (unsigned short*)(ws + WS_BIAS);
    float* outp = (float*)d_out;

    hipMemsetAsync(d_ws, 0, (size_t)WS_ZERO_FLOATS * sizeof(float), stream);

    setup_kernel<<<1, 256, 0, stream>>>(batch, offsets, intra);
    scatter_kernel<<<N_NODES, 128, 0, stream>>>(x, pe_re, pe_im, batch, intra, hd, ar, ai, mask);
    prep_kernel<<<512, 256, 0, stream>>>(ar, ai, pn, cn, kf_hi, kf_lo);

    gemm_kernel<128, 128, false, false><<<256, 256, 0, stream>>>(hd, wq, bq, nullptr, qm);
    gemm_kernel<128, 128, false, false><<<256, 256, 0, stream>>>(hd, wk, bk, nullptr, km);
    gemm_kernel<128, 128, false, false><<<256, 256, 0, stream>>>(hd, wv, bv, nullptr, vm);

    bias_kernel<<<dim3(16, 32), 512, 0, stream>>>(cn, pn, kf_hi, kf_lo,
                                                  pe_w1, pe_b1, pe_w2, pe_b2, bias);

    attn_kernel<<<dim3(M_MAX / QT, B_G), 256, 0, stream>>>(qm, km, vm, mask, bias, oatt);

    gemm_kernel<128, 128, false, false><<<256, 256, 0, stream>>>(oatt, wo, bo, nullptr, oprj);
    gather_res_ln_kernel<<<N_NODES, 128, 0, stream>>>(oprj, x, batch, intra, ln2_g, ln2_b, hln);
    gemm_kernel<128, 256, true,  false><<<160, 256, 0, stream>>>(hln, mlp_w1, mlp_b1, nullptr, ffnh);
    gemm_kernel<256, 128, false, true ><<<160, 256, 0, stream>>>(ffnh, mlp_w2, mlp_b2, hln, ffno);
    ln_kernel<<<N_NODES, 128, 0, stream>>>(ffno, ln3_g, ln3_b, outp);
}

// Round 6
// 315.131 us; speedup vs baseline: 2.2326x; 1.0646x over previous
//
#include <hip/hip_runtime.h>

// ---------------- problem constants ----------------
#define N_NODES 5120
#define C_DIM   128
#define D_PE    16
#define M_MAX   256
#define B_G     32
#define H_HEADS 8
#define DH      16
#define EPS_PE  1e-8f
#define QT      4
#define SCP     264   // padded score stride (kills 4-way PV bank conflict)

// ---------------- ws layout (float units) ----------------
#define WS_COUNTS   0
#define WS_OFFSETS  32
#define WS_INTRA    64
#define WS_MASK     5184
#define WS_HD       13376      // B*M*C = 1048576
#define WS_AR       1061952    // 131072
#define WS_AI       1193024    // 131072
#define WS_PN       1324096    // 131072
#define WS_CN       1455168    // B*M*32 = 262144 (f32 unit complex [cr|ci])
#define WS_KFHI     1717312    // B*M*64 bf16 = 262144 f
#define WS_KFLO     1979456    // B*M*32 bf16 = 131072 f
#define WS_Q        2110528    // 1048576
#define WS_K        3159104
#define WS_V        4207680
#define WS_OATT     5256256
#define WS_OPROJ    6304832
#define WS_HLN      7353408    // 655360
#define WS_FFNH     8008768    // 1310720
#define WS_FFNO     9319488    // 655360
#define WS_BIAS     9974848    // B*M*M*8 bf16 = 8388608 f
#define WS_WPK_HI   18363456   // 131072 shorts = 65536 f
#define WS_WPK_LO   18428992   // 131072 shorts = 65536 f
#define WS_ZERO_FLOATS 1324096 // counts..ai zeroed each call

// packed-weight offsets (shorts): q,k,v:128x128; o:128x128; w1:128x256; w2:256x128
#define WOFF_Q   0
#define WOFF_K   16384
#define WOFF_V   32768
#define WOFF_O   49152
#define WOFF_W1  65536
#define WOFF_W2  98304

typedef __attribute__((ext_vector_type(8))) short bf8_t;
typedef __attribute__((ext_vector_type(4))) float f4_t;

__device__ inline short f2bf(float f) {
    union { float f; unsigned u; } v; v.f = f;
    unsigned r = (v.u + 0x7FFF + ((v.u >> 16) & 1)) >> 16;
    return (short)r;
}
__device__ inline float bf2f(short h) {
    union { unsigned u; float f; } v; v.u = ((unsigned)(unsigned short)h) << 16;
    return v.f;
}
__device__ inline unsigned pack2(short a, short b) {
    return (unsigned)(unsigned short)a | ((unsigned)(unsigned short)b << 16);
}
__device__ inline bf8_t bf8_from2(uint2 a, uint2 b) {
    bf8_t o;
    o[0]=(short)a.x; o[1]=(short)(a.x>>16); o[2]=(short)a.y; o[3]=(short)(a.y>>16);
    o[4]=(short)b.x; o[5]=(short)(b.x>>16); o[6]=(short)b.y; o[7]=(short)(b.y>>16);
    return o;
}

// ---------------- setup: counts -> offsets -> intra ----------------
__global__ __launch_bounds__(256) void setup_kernel(
    const int* __restrict__ batch, int* __restrict__ offsets, int* __restrict__ intra)
{
    __shared__ int cnt[B_G];
    __shared__ int off[B_G];
    const int t = threadIdx.x;
    if (t < B_G) cnt[t] = 0;
    __syncthreads();
    for (int n = t; n < N_NODES; n += 256) atomicAdd(&cnt[batch[n]], 1);
    __syncthreads();
    if (t == 0) { int s = 0; for (int b = 0; b < B_G; ++b) { off[b] = s; s += cnt[b]; } }
    __syncthreads();
    if (t < B_G) offsets[t] = off[t];
    for (int n = t; n < N_NODES; n += 256) intra[n] = n - off[batch[n]];
}

// ---------------- scatter ragged -> dense ----------------
__global__ __launch_bounds__(128) void scatter_kernel(
    const float* __restrict__ x, const float* __restrict__ pre, const float* __restrict__ pim,
    const int* __restrict__ batch, const int* __restrict__ intra,
    float* __restrict__ hd, float* __restrict__ ar, float* __restrict__ ai,
    int* __restrict__ mask)
{
    const int n = blockIdx.x, c = threadIdx.x;
    const int b = batch[n], m = intra[n];
    hd[((size_t)b * M_MAX + m) * C_DIM + c] = x[(size_t)n * C_DIM + c];
    if (c < D_PE) {
        ar[((size_t)b * M_MAX + m) * D_PE + c] = pre[(size_t)n * D_PE + c];
        ai[((size_t)b * M_MAX + m) * D_PE + c] = pim[(size_t)n * D_PE + c];
    }
    if (c == 0) mask[b * M_MAX + m] = 1;
}

// ---------------- prep: pn, unit complex, key features (bf16 hi/lo) ----------------
__global__ __launch_bounds__(256) void prep_kernel(
    const float* __restrict__ ar, const float* __restrict__ ai,
    float* __restrict__ pn, float* __restrict__ cn,
    unsigned short* __restrict__ kf_hi, unsigned short* __restrict__ kf_lo)
{
    const int idx = blockIdx.x * 256 + threadIdx.x;     // B*M*16 = 131072
    const int cell = idx >> 4, dd = idx & 15;
    const float a = ar[idx], b = ai[idx];
    const float p = sqrtf(a * a + b * b + EPS_PE);
    const float inv = 1.f / p;
    const float cr = a * inv, ci = b * inv;
    pn[idx] = p;
    cn[(size_t)cell * 32 + dd]      = cr;
    cn[(size_t)cell * 32 + 16 + dd] = ci;
    const size_t hb = (size_t)cell * 64, lb = (size_t)cell * 32;
    short crh = f2bf(cr), cih = f2bf(ci);
    kf_hi[hb + dd]      = (unsigned short)crh;
    kf_hi[hb + 16 + dd] = (unsigned short)cih;
    kf_hi[hb + 32 + dd] = (unsigned short)f2bf(p);
    kf_hi[hb + 48 + dd] = (dd == 0) ? (unsigned short)f2bf(1.f) : 0;
    kf_lo[lb + dd]      = (unsigned short)f2bf(cr - bf2f(crh));
    kf_lo[lb + 16 + dd] = (unsigned short)f2bf(ci - bf2f(cih));
}

// ---------------- weight packing: fp32 W -> MFMA frag layout, bf16 hi/lo ----------------
// B-frag for tile (kt,nt): lane holds W[kt*32 + (lane>>4)*8 + e][nt*16 + (lane&15)], e=0..7
// tiles: q(32) k(32) v(32) o(32) | w1(64, N=256) | w2(64, K=256)
__global__ __launch_bounds__(256) void wpack_kernel(
    const float* __restrict__ wq, const float* __restrict__ wk,
    const float* __restrict__ wv, const float* __restrict__ wo,
    const float* __restrict__ w1, const float* __restrict__ w2,
    unsigned short* __restrict__ hi, unsigned short* __restrict__ lo)
{
    const int tid = blockIdx.x * 256 + threadIdx.x;   // 256 tiles * 64 lanes = 16384
    const int tile = tid >> 6, lane = tid & 63;
    const float* W; int N, ltile; size_t off;
    if (tile < 128) {
        const int wi = tile >> 5; ltile = tile & 31; N = 128;
        W = (wi == 0) ? wq : (wi == 1) ? wk : (wi == 2) ? wv : wo;
        off = (size_t)wi * 16384;
    } else if (tile < 192) { ltile = tile - 128; N = 256; W = w1; off = WOFF_W1; }
    else                   { ltile = tile - 192; N = 128; W = w2; off = WOFF_W2; }
    const int NT = N / 16;
    const int kt = ltile / NT, nt = ltile % NT;
    const int col = nt * 16 + (lane & 15);
    const int k0  = kt * 32 + (lane >> 4) * 8;
    bf8_t vhi, vlo;
    #pragma unroll
    for (int e = 0; e < 8; ++e) {
        const float v = W[(size_t)(k0 + e) * N + col];
        const short h = f2bf(v);
        vhi[e] = h; vlo[e] = f2bf(v - bf2f(h));
    }
    const size_t toff = off + ((size_t)ltile * 64 + lane) * 8;
    *(bf8_t*)(hi + toff) = vhi;
    *(bf8_t*)(lo + toff) = vlo;
}

// ---------------- MFMA GEMM body: out = act(A@W + bias) [+res], split-bf16 ----------------
template<int K, int N, bool RELU, bool RES>
__device__ inline void mgemm_body(
    const float* __restrict__ A, const unsigned short* __restrict__ hi,
    const unsigned short* __restrict__ lo,
    const float* __restrict__ bias, const float* __restrict__ res,
    float* __restrict__ out, int bx)
{
    constexpr int NT = N / 16, KT = K / 32;
    const int rb = bx * 64;
    const int w = threadIdx.x >> 6, lane = threadIdx.x & 63;
    const int arow = rb + w * 16 + (lane & 15);
    const int g = lane >> 4;

    f4_t acc[NT];
    #pragma unroll
    for (int nt = 0; nt < NT; ++nt) acc[nt] = (f4_t){0.f, 0.f, 0.f, 0.f};

    #pragma unroll
    for (int kt = 0; kt < KT; ++kt) {
        const float* ap = A + (size_t)arow * K + kt * 32 + g * 8;
        const float4 a0 = *(const float4*)ap;
        const float4 a1 = *(const float4*)(ap + 4);
        const float av[8] = {a0.x, a0.y, a0.z, a0.w, a1.x, a1.y, a1.z, a1.w};
        bf8_t ahi, alo;
        #pragma unroll
        for (int e = 0; e < 8; ++e) {
            const short h = f2bf(av[e]);
            ahi[e] = h; alo[e] = f2bf(av[e] - bf2f(h));
        }
        #pragma unroll
        for (int nt = 0; nt < NT; ++nt) {
            const size_t toff = ((size_t)(kt * NT + nt) * 64 + lane) * 8;
            const bf8_t bhi = *(const bf8_t*)(hi + toff);
            const bf8_t blo = *(const bf8_t*)(lo + toff);
            acc[nt] = __builtin_amdgcn_mfma_f32_16x16x32_bf16(ahi, bhi, acc[nt], 0, 0, 0);
            acc[nt] = __builtin_amdgcn_mfma_f32_16x16x32_bf16(alo, bhi, acc[nt], 0, 0, 0);
            acc[nt] = __builtin_amdgcn_mfma_f32_16x16x32_bf16(ahi, blo, acc[nt], 0, 0, 0);
        }
    }

    const int orow0 = rb + w * 16 + g * 4;
    #pragma unroll
    for (int nt = 0; nt < NT; ++nt) {
        const int col = nt * 16 + (lane & 15);
        const float bv = bias[col];
        #pragma unroll
        for (int r = 0; r < 4; ++r) {
            float v = acc[nt][r] + bv;
            if (RELU) v = fmaxf(v, 0.f);
            if (RES)  v += res[(size_t)(orow0 + r) * N + col];
            out[(size_t)(orow0 + r) * N + col] = v;
        }
    }
}

// fused QKV (shared A = hd), grid (rows/64, 3)
__global__ __launch_bounds__(256) void qkv_kernel(
    const float* __restrict__ A,
    const unsigned short* __restrict__ hi, const unsigned short* __restrict__ lo,
    const float* __restrict__ bq, const float* __restrict__ bk, const float* __restrict__ bv,
    float* __restrict__ qm, float* __restrict__ km, float* __restrict__ vm)
{
    const int sel = blockIdx.y;
    const float* bias = (sel == 0) ? bq : (sel == 1) ? bk : bv;
    float* out = (sel == 0) ? qm : (sel == 1) ? km : vm;
    const size_t woff = (size_t)sel * 16384;
    mgemm_body<128, 128, false, false>(A, hi + woff, lo + woff, bias, nullptr, out, blockIdx.x);
}

template<int K, int N, bool RELU, bool RES>
__global__ __launch_bounds__(256) void mgemm_kernel(
    const float* __restrict__ A,
    const unsigned short* __restrict__ hi, const unsigned short* __restrict__ lo,
    const float* __restrict__ bias, const float* __restrict__ res, float* __restrict__ out)
{
    mgemm_body<K, N, RELU, RES>(A, hi, lo, bias, res, out, blockIdx.x);
}

// ---------------- MFMA pairwise-bias kernel (unchanged, validated) ----------------
__global__ __launch_bounds__(512) void bias_kernel(
    const float* __restrict__ cn, const float* __restrict__ pn,
    const unsigned short* __restrict__ kf_hi, const unsigned short* __restrict__ kf_lo,
    const float* __restrict__ w1, const float* __restrict__ b1,
    const float* __restrict__ w2, const float* __restrict__ b2,
    unsigned short* __restrict__ bias_out)
{
    __shared__ float sW1T[32][65];
    __shared__ float s_cn[16][32];
    __shared__ float s_pn[16][16];
    __shared__ uint2 s_scr[8][16][10];

    const int b  = blockIdx.y;
    const int i0 = blockIdx.x * 16;
    const int t  = threadIdx.x;

    for (int idx = t; idx < 2048; idx += 512) {
        int f = idx >> 5, hh = idx & 31;
        sW1T[hh][f] = w1[f * 32 + hh];
    }
    { int il = t >> 5, c = t & 31;
      s_cn[il][c] = cn[((size_t)(b * 256 + i0 + il)) * 32 + c]; }
    if (t < 256) { int il = t >> 4, dd = t & 15;
      s_pn[il][dd] = pn[((size_t)(b * 256 + i0 + il)) * 16 + dd]; }
    __syncthreads();

    const int w    = t >> 6;
    const int lane = t & 63;
    const int lj   = lane & 15;
    const int g    = lane >> 4;

    bf8_t a2f;
    #pragma unroll
    for (int e = 0; e < 8; ++e) {
        float v = (lj < 8) ? w2[(g * 8 + e) * 8 + lj] : 0.f;
        a2f[e] = f2bf(v);
    }
    float b2v0 = 0.f, b2v1 = 0.f, b2v2 = 0.f, b2v3 = 0.f;
    if (g < 2) { b2v0 = b2[g*4+0]; b2v1 = b2[g*4+1]; b2v2 = b2[g*4+2]; b2v3 = b2[g*4+3]; }

    for (int ii = 0; ii < 2; ++ii) {
        const int il = w * 2 + ii;
        const int i  = i0 + il;

        float vrow0 = b1[lj], vrow1 = b1[16 + lj];
        #pragma unroll
        for (int dd = 0; dd < 16; ++dd) {
            float p = s_pn[il][dd];
            vrow0 = fmaf(sW1T[lj][16 + dd],      p, vrow0);
            vrow1 = fmaf(sW1T[16 + lj][16 + dd], p, vrow1);
        }

        bf8_t a0hi0, a0lo0, a1f0, a0hi1, a0lo1, a1f1;
        #pragma unroll
        for (int e = 0; e < 8; ++e) {
            const int dd = (g & 1) * 8 + e;
            const float cr = s_cn[il][dd], ci = s_cn[il][16 + dd];
            {
                float wr = sW1T[lj][32 + dd], wi = sW1T[lj][48 + dd];
                float val = (g < 2) ? (wr * cr - wi * ci) : (wr * ci + wi * cr);
                short hi = f2bf(val);
                a0hi0[e] = hi; a0lo0[e] = f2bf(val - bf2f(hi));
                float v1 = (g < 2) ? sW1T[lj][g * 8 + e]
                                   : ((g == 2 && e == 0) ? vrow0 : 0.f);
                a1f0[e] = f2bf(v1);
            }
            {
                float wr = sW1T[16 + lj][32 + dd], wi = sW1T[16 + lj][48 + dd];
                float val = (g < 2) ? (wr * cr - wi * ci) : (wr * ci + wi * cr);
                short hi = f2bf(val);
                a0hi1[e] = hi; a0lo1[e] = f2bf(val - bf2f(hi));
                float v1 = (g < 2) ? sW1T[16 + lj][g * 8 + e]
                                   : ((g == 2 && e == 0) ? vrow1 : 0.f);
                a1f1[e] = f2bf(v1);
            }
        }

        for (int jt = 0; jt < 16; ++jt) {
            const size_t node = (size_t)b * 256 + jt * 16 + lj;
            const bf8_t* ph = (const bf8_t*)(kf_hi + node * 64);
            const bf8_t* pl = (const bf8_t*)(kf_lo + node * 32);
            bf8_t b0hi = ph[g];
            bf8_t b0lo = pl[g];
            bf8_t b1f  = ph[4 + g];

            f4_t acc0 = {0.f, 0.f, 0.f, 0.f}, acc1 = {0.f, 0.f, 0.f, 0.f};
            acc0 = __builtin_amdgcn_mfma_f32_16x16x32_bf16(a0hi0, b0hi, acc0, 0, 0, 0);
            acc0 = __builtin_amdgcn_mfma_f32_16x16x32_bf16(a0hi0, b0lo, acc0, 0, 0, 0);
            acc0 = __builtin_amdgcn_mfma_f32_16x16x32_bf16(a0lo0, b0hi, acc0, 0, 0, 0);
            acc0 = __builtin_amdgcn_mfma_f32_16x16x32_bf16(a1f0,  b1f,  acc0, 0, 0, 0);
            acc1 = __builtin_amdgcn_mfma_f32_16x16x32_bf16(a0hi1, b0hi, acc1, 0, 0, 0);
            acc1 = __builtin_amdgcn_mfma_f32_16x16x32_bf16(a0hi1, b0lo, acc1, 0, 0, 0);
            acc1 = __builtin_amdgcn_mfma_f32_16x16x32_bf16(a0lo1, b0hi, acc1, 0, 0, 0);
            acc1 = __builtin_amdgcn_mfma_f32_16x16x32_bf16(a1f1,  b1f,  acc1, 0, 0, 0);

            uint2 w0, w1p;
            w0.x  = pack2(f2bf(fmaxf(acc0[0], 0.f)), f2bf(fmaxf(acc0[1], 0.f)));
            w0.y  = pack2(f2bf(fmaxf(acc0[2], 0.f)), f2bf(fmaxf(acc0[3], 0.f)));
            w1p.x = pack2(f2bf(fmaxf(acc1[0], 0.f)), f2bf(fmaxf(acc1[1], 0.f)));
            w1p.y = pack2(f2bf(fmaxf(acc1[2], 0.f)), f2bf(fmaxf(acc1[3], 0.f)));
            s_scr[w][lj][g]     = w0;
            s_scr[w][lj][4 + g] = w1p;
            __builtin_amdgcn_s_waitcnt(0);

            uint2 q0 = s_scr[w][lj][2 * g];
            uint2 q1 = s_scr[w][lj][2 * g + 1];
            bf8_t hb = bf8_from2(q0, q1);

            f4_t acc2 = {0.f, 0.f, 0.f, 0.f};
            acc2 = __builtin_amdgcn_mfma_f32_16x16x32_bf16(a2f, hb, acc2, 0, 0, 0);

            if (g < 2) {
                uint2 st;
                st.x = pack2(f2bf(acc2[0] + b2v0), f2bf(acc2[1] + b2v1));
                st.y = pack2(f2bf(acc2[2] + b2v2), f2bf(acc2[3] + b2v3));
                size_t idx = (((size_t)b * 256 + i) * 256 + jt * 16 + lj) * 8 + g * 4;
                *(uint2*)(bias_out + idx) = st;
            }
        }
    }
}

// ---------------- attention (bias from global, fp32 VALU) ----------------
__global__ __launch_bounds__(256) void attn_kernel(
    const float* __restrict__ qm, const float* __restrict__ km, const float* __restrict__ vm,
    const int* __restrict__ mask, const unsigned short* __restrict__ bias,
    float* __restrict__ o_att)
{
    const int b  = blockIdx.y;
    const int i0 = blockIdx.x * QT;
    const int t  = threadIdx.x;
    const int j  = t;

    __shared__ float s_q[QT][C_DIM];
    __shared__ float s_sc[QT][H_HEADS][SCP];

    for (int idx = t; idx < QT * C_DIM; idx += 256) {
        const int qi = idx >> 7, c = idx & 127;
        s_q[qi][c] = qm[((size_t)(b * 256 + i0 + qi)) * C_DIM + c];
    }
    __syncthreads();

    const int mj = mask[b * M_MAX + j];
    uint4 bu[QT];
    #pragma unroll
    for (int qi = 0; qi < QT; ++qi)
        bu[qi] = *(const uint4*)(bias + (((size_t)(b * 256 + i0 + qi)) * 256 + j) * 8);

    const float* krow = km + ((size_t)(b * 256 + j)) * C_DIM;
    #pragma unroll
    for (int h = 0; h < 8; ++h) {
        float kv[DH];
        #pragma unroll
        for (int q4 = 0; q4 < 4; ++q4) {
            float4 v = ((const float4*)(krow + h * DH))[q4];
            kv[q4*4+0]=v.x; kv[q4*4+1]=v.y; kv[q4*4+2]=v.z; kv[q4*4+3]=v.w;
        }
        #pragma unroll
        for (int qi = 0; qi < QT; ++qi) {
            float dot = 0.f;
            #pragma unroll
            for (int dd = 0; dd < DH; ++dd)
                dot = fmaf(s_q[qi][h * DH + dd], kv[dd], dot);
            const unsigned u = ((const unsigned*)&bu[qi])[h >> 1];
            const float bv = bf2f((short)((h & 1) ? (u >> 16) : (u & 0xffff)));
            s_sc[qi][h][j] = mj ? fmaf(dot, 0.25f, bv) : -1e9f;
        }
    }
    __syncthreads();

    {
        const int wave = t >> 6, lane = t & 63;
        for (int r = wave; r < QT * H_HEADS; r += 4) {
            float* row = ((float*)s_sc) + r * SCP;
            float x0 = row[lane], x1 = row[lane + 64], x2 = row[lane + 128], x3 = row[lane + 192];
            float mx = fmaxf(fmaxf(x0, x1), fmaxf(x2, x3));
            #pragma unroll
            for (int off = 32; off > 0; off >>= 1) mx = fmaxf(mx, __shfl_xor(mx, off, 64));
            float e0 = expf(x0 - mx), e1 = expf(x1 - mx), e2 = expf(x2 - mx), e3 = expf(x3 - mx);
            float s = e0 + e1 + e2 + e3;
            #pragma unroll
            for (int off = 32; off > 0; off >>= 1) s += __shfl_xor(s, off, 64);
            const float inv = 1.f / s;
            row[lane] = e0 * inv; row[lane + 64] = e1 * inv;
            row[lane + 128] = e2 * inv; row[lane + 192] = e3 * inv;
        }
    }
    __syncthreads();

    {
        const int c = t & 127;
        const int gq = t >> 7;
        const int h = c >> 4;
        const int qA = gq * 2, qB = gq * 2 + 1;
        const float* vb = vm + (size_t)b * M_MAX * C_DIM + c;
        float a0 = 0.f, a1 = 0.f;
        for (int jj = 0; jj < M_MAX; jj += 4) {
            float4 pA = *(const float4*)&s_sc[qA][h][jj];
            float4 pB = *(const float4*)&s_sc[qB][h][jj];
            float v0 = vb[(size_t)(jj + 0) * C_DIM];
            float v1 = vb[(size_t)(jj + 1) * C_DIM];
            float v2 = vb[(size_t)(jj + 2) * C_DIM];
            float v3 = vb[(size_t)(jj + 3) * C_DIM];
            a0 = fmaf(pA.x, v0, a0); a0 = fmaf(pA.y, v1, a0);
            a0 = fmaf(pA.z, v2, a0); a0 = fmaf(pA.w, v3, a0);
            a1 = fmaf(pB.x, v0, a1); a1 = fmaf(pB.y, v1, a1);
            a1 = fmaf(pB.z, v2, a1); a1 = fmaf(pB.w, v3, a1);
        }
        o_att[((size_t)(b * 256 + i0 + qA)) * C_DIM + c] = a0;
        o_att[((size_t)(b * 256 + i0 + qB)) * C_DIM + c] = a1;
    }
}

// ---------------- gather + residual + LayerNorm ----------------
__global__ __launch_bounds__(128) void gather_res_ln_kernel(
    const float* __restrict__ op, const float* __restrict__ x,
    const int* __restrict__ batch, const int* __restrict__ intra,
    const float* __restrict__ g, const float* __restrict__ be, float* __restrict__ out)
{
    const int n = blockIdx.x, c = threadIdx.x;
    const int b = batch[n], m = intra[n];
    const float v = op[((size_t)b * M_MAX + m) * C_DIM + c] + x[(size_t)n * C_DIM + c];
    float s = v, sq = v * v;
    #pragma unroll
    for (int off = 32; off > 0; off >>= 1) {
        s  += __shfl_xor(s, off, 64);
        sq += __shfl_xor(sq, off, 64);
    }
    __shared__ float red[4];
    if ((threadIdx.x & 63) == 0) {
        red[(threadIdx.x >> 6) * 2]     = s;
        red[(threadIdx.x >> 6) * 2 + 1] = sq;
    }
    __syncthreads();
    s = red[0] + red[2]; sq = red[1] + red[3];
    const float mu  = s * (1.f / C_DIM);
    const float var = sq * (1.f / C_DIM) - mu * mu;
    const float sc  = rsqrtf(var + 1e-5f);
    out[(size_t)n * C_DIM + c] = (v - mu) * sc * g[c] + be[c];
}

__global__ __launch_bounds__(128) void ln_kernel(
    const float* __restrict__ in, const float* __restrict__ g,
    const float* __restrict__ be, float* __restrict__ out)
{
    const int n = blockIdx.x, c = threadIdx.x;
    const float v = in[(size_t)n * C_DIM + c];
    float s = v, sq = v * v;
    #pragma unroll
    for (int off = 32; off > 0; off >>= 1) {
        s  += __shfl_xor(s, off, 64);
        sq += __shfl_xor(sq, off, 64);
    }
    __shared__ float red[4];
    if ((threadIdx.x & 63) == 0) {
        red[(threadIdx.x >> 6) * 2]     = s;
        red[(threadIdx.x >> 6) * 2 + 1] = sq;
    }
    __syncthreads();
    s = red[0] + red[2]; sq = red[1] + red[3];
    const float mu  = s * (1.f / C_DIM);
    const float var = sq * (1.f / C_DIM) - mu * mu;
    const float sc  = rsqrtf(var + 1e-5f);
    out[(size_t)n * C_DIM + c] = (v - mu) * sc * g[c] + be[c];
}

// ---------------- launch ----------------
extern "C" void kernel_launch(void* const* d_in, const int* in_sizes, int n_in,
                              void* d_out, int out_size, void* d_ws, size_t ws_size,
                              hipStream_t stream)
{
    const float* x      = (const float*)d_in[0];
    const float* pe_re  = (const float*)d_in[1];
    const float* pe_im  = (const float*)d_in[2];
    const float* wq     = (const float*)d_in[3];
    const float* bq     = (const float*)d_in[4];
    const float* wk     = (const float*)d_in[5];
    const float* bk     = (const float*)d_in[6];
    const float* wv     = (const float*)d_in[7];
    const float* bv     = (const float*)d_in[8];
    const float* wo     = (const float*)d_in[9];
    const float* bo     = (const float*)d_in[10];
    const float* pe_w1  = (const float*)d_in[11];
    const float* pe_b1  = (const float*)d_in[12];
    const float* pe_w2  = (const float*)d_in[13];
    const float* pe_b2  = (const float*)d_in[14];
    const float* mlp_w1 = (const float*)d_in[15];
    const float* mlp_b1 = (const float*)d_in[16];
    const float* mlp_w2 = (const float*)d_in[17];
    const float* mlp_b2 = (const float*)d_in[18];
    const float* ln2_g  = (const float*)d_in[19];
    const float* ln2_b  = (const float*)d_in[20];
    const float* ln3_g  = (const float*)d_in[21];
    const float* ln3_b  = (const float*)d_in[22];
    const int*   batch  = (const int*)d_in[23];

    float* ws = (float*)d_ws;
    int*   offsets = (int*)(ws + WS_OFFSETS);
    int*   intra   = (int*)(ws + WS_INTRA);
    int*   mask    = (int*)(ws + WS_MASK);
    float* hd   = ws + WS_HD;
    float* ar   = ws + WS_AR;
    float* ai   = ws + WS_AI;
    float* pn   = ws + WS_PN;
    float* cn   = ws + WS_CN;
    unsigned short* kf_hi = (unsigned short*)(ws + WS_KFHI);
    unsigned short* kf_lo = (unsigned short*)(ws + WS_KFLO);
    float* qm   = ws + WS_Q;
    float* km   = ws + WS_K;
    float* vm   = ws + WS_V;
    float* oatt = ws + WS_OATT;
    float* oprj = ws + WS_OPROJ;
    float* hln  = ws + WS_HLN;
    float* ffnh = ws + WS_FFNH;
    float* ffno = ws + WS_FFNO;
    unsigned short* bias = (unsigned short*)(ws + WS_BIAS);
    unsigned short* wpk_hi = (unsigned short*)(ws + WS_WPK_HI);
    unsigned short* wpk_lo = (unsigned short*)(ws + WS_WPK_LO);
    float* outp = (float*)d_out;

    hipMemsetAsync(d_ws, 0, (size_t)WS_ZERO_FLOATS * sizeof(float), stream);

    setup_kernel<<<1, 256, 0, stream>>>(batch, offsets, intra);
    wpack_kernel<<<64, 256, 0, stream>>>(wq, wk, wv, wo, mlp_w1, mlp_w2, wpk_hi, wpk_lo);
    scatter_kernel<<<N_NODES, 128, 0, stream>>>(x, pe_re, pe_im, batch, intra, hd, ar, ai, mask);
    prep_kernel<<<512, 256, 0, stream>>>(ar, ai, pn, cn, kf_hi, kf_lo);

    qkv_kernel<<<dim3(128, 3), 256, 0, stream>>>(hd, wpk_hi, wpk_lo, bq, bk, bv, qm, km, vm);

    bias_kernel<<<dim3(16, 32), 512, 0, stream>>>(cn, pn, kf_hi, kf_lo,
                                                  pe_w1, pe_b1, pe_w2, pe_b2, bias);

    attn_kernel<<<dim3(M_MAX / QT, B_G), 256, 0, stream>>>(qm, km, vm, mask, bias, oatt);

    mgemm_kernel<128, 128, false, false><<<128, 256, 0, stream>>>(
        oatt, wpk_hi + WOFF_O, wpk_lo + WOFF_O, bo, nullptr, oprj);
    gather_res_ln_kernel<<<N_NODES, 128, 0, stream>>>(oprj, x, batch, intra, ln2_g, ln2_b, hln);
    mgemm_kernel<128, 256, true, false><<<80, 256, 0, stream>>>(
        hln, wpk_hi + WOFF_W1, wpk_lo + WOFF_W1, mlp_b1, nullptr, ffnh);
    mgemm_kernel<256, 128, false, true><<<80, 256, 0, stream>>>(
        ffnh, wpk_hi + WOFF_W2, wpk_lo + WOFF_W2, mlp_b2, hln, ffno);
    ln_kernel<<<N_NODES, 128, 0, stream>>>(ffno, ln3_g, ln3_b, outp);
}